// Round 3
// baseline (478.563 us; speedup 1.0000x reference)
//
#include <hip/hip_runtime.h>
#include <hip/hip_bf16.h>
#include <cmath>

#define N_NODES 8192
#define E_EDGES 262144
#define NFEAT   512
#define NHID    256

typedef __attribute__((ext_vector_type(8))) short short8;
typedef __attribute__((ext_vector_type(4))) float f32x4;
typedef __attribute__((ext_vector_type(4))) short short4v;

// f32 -> bf16 with round-to-nearest-even (cheap integer form)
static __device__ inline unsigned short f2bf(float f) {
    union { float f; unsigned u; } v; v.f = f;
    unsigned r = v.u + 0x7FFFu + ((v.u >> 16) & 1u);
    return (unsigned short)(r >> 16);
}

// ---------------------------------------------------------------------------
// Pre-convert W_lin [256,512] f32 -> bf16 (row-major unchanged). W is reused
// by every m-block; converting once avoids per-block VALU conversion cost.
// ---------------------------------------------------------------------------
__global__ __launch_bounds__(256) void convw_kernel(
        const float* __restrict__ W, unsigned short* __restrict__ Wbf) {
    const int i = (blockIdx.x * 256 + threadIdx.x) * 4;   // 131072 elems total
    const float4 w = *reinterpret_cast<const float4*>(&W[i]);
    short4v o;
    o[0] = (short)f2bf(w.x); o[1] = (short)f2bf(w.y);
    o[2] = (short)f2bf(w.z); o[3] = (short)f2bf(w.w);
    *reinterpret_cast<short4v*>(&Wbf[i]) = o;
}

// ---------------------------------------------------------------------------
// Fused: h = x @ W^T + b (bf16 MFMA), then s = h.Wa[:256], t = h.Wa[256:]
// computed from the accumulators in-register (no h re-read, no extra kernel).
//
// Block = 256 thr = 4 waves; each wave owns a 16-row strip of h and ALL
// 256 cols (16 n-tiles). mfma_f32_16x16x32_bf16 layouts (m89-verified):
//   A frag: lane l holds A[l&15][(l>>4)*8 + j], j=0..7
//   B frag: lane l holds B^T-row (l&15) = W col slice, same k packing
//   C/D:    lane l reg j = D[(l>>4)*4 + j][l&15]
// ---------------------------------------------------------------------------
__global__ __launch_bounds__(256) void gemm_fused_kernel(
        const float* __restrict__ x,            // [8192, 512] f32
        const unsigned short* __restrict__ Wbf, // [256, 512] bf16 bits
        const float* __restrict__ b,            // [256]
        const float* __restrict__ Wa,           // [512]
        float* __restrict__ hout,               // [8192, 256]
        float* __restrict__ s, float* __restrict__ t) {
    const int lane = threadIdx.x & 63;
    const int wave = threadIdx.x >> 6;
    const int r    = lane & 15;              // A-row / B-col within tile
    const int kg   = lane >> 4;              // k-group 0..3
    const int m0   = blockIdx.x * 64 + wave * 16;

    f32x4 acc[16];
    #pragma unroll
    for (int nt = 0; nt < 16; ++nt) acc[nt] = (f32x4)0.0f;

    const float* xrow = x + (size_t)(m0 + r) * NFEAT + kg * 8;

    for (int ks = 0; ks < NFEAT / 32; ++ks) {
        const int k0 = ks * 32;
        // a_frag: 8 contiguous f32 -> bf16 (each x element converted once
        // across the whole grid, so inline conversion is cheap here).
        short8 af;
        {
            const float4 a0 = *reinterpret_cast<const float4*>(xrow + k0);
            const float4 a1 = *reinterpret_cast<const float4*>(xrow + k0 + 4);
            af[0] = (short)f2bf(a0.x); af[1] = (short)f2bf(a0.y);
            af[2] = (short)f2bf(a0.z); af[3] = (short)f2bf(a0.w);
            af[4] = (short)f2bf(a1.x); af[5] = (short)f2bf(a1.y);
            af[6] = (short)f2bf(a1.z); af[7] = (short)f2bf(a1.w);
        }
        #pragma unroll
        for (int nt = 0; nt < 16; ++nt) {
            // b_frag: Wbf[nt*16+r][k0 + kg*8 .. +8)  -> one dwordx4 load
            const short8 bf = *reinterpret_cast<const short8*>(
                &Wbf[(size_t)(nt * 16 + r) * NFEAT + k0 + kg * 8]);
            acc[nt] = __builtin_amdgcn_mfma_f32_16x16x32_bf16(af, bf, acc[nt], 0, 0, 0);
        }
    }

    // Epilogue: bias, h store, and in-register s/t partial dots.
    float sp[4] = {0.f, 0.f, 0.f, 0.f};
    float tp[4] = {0.f, 0.f, 0.f, 0.f};
    #pragma unroll
    for (int nt = 0; nt < 16; ++nt) {
        const int n   = nt * 16 + r;
        const float bb  = b[n];
        const float was = Wa[n];
        const float wat = Wa[NHID + n];
        #pragma unroll
        for (int j = 0; j < 4; ++j) {
            const float hv = acc[nt][j] + bb;
            hout[(size_t)(m0 + kg * 4 + j) * NHID + n] = hv;
            sp[j] = fmaf(hv, was, sp[j]);
            tp[j] = fmaf(hv, wat, tp[j]);
        }
    }
    // Reduce across the 16 lanes (r = 0..15) sharing each row.
    #pragma unroll
    for (int off = 1; off < 16; off <<= 1) {
        #pragma unroll
        for (int j = 0; j < 4; ++j) {
            sp[j] += __shfl_xor(sp[j], off);
            tp[j] += __shfl_xor(tp[j], off);
        }
    }
    if (r == 0) {
        #pragma unroll
        for (int j = 0; j < 4; ++j) {
            const int m = m0 + kg * 4 + j;
            s[m] = sp[j];
            t[m] = tp[j];
        }
    }
}

// ---------------------------------------------------------------------------
// out[src,dst] = tanh(s[src] + t[dst]); adj==1 at every edge by construction.
// ---------------------------------------------------------------------------
__global__ __launch_bounds__(256) void edge_kernel(
        const int* __restrict__ ei,
        const float* __restrict__ s, const float* __restrict__ t,
        float* __restrict__ out) {
    const int e = blockIdx.x * blockDim.x + threadIdx.x;
    if (e >= E_EDGES) return;
    const int src = ei[e];
    const int dst = ei[E_EDGES + e];
    out[(size_t)src * N_NODES + dst] = tanhf(s[src] + t[dst]);
}

extern "C" void kernel_launch(void* const* d_in, const int* in_sizes, int n_in,
                              void* d_out, int out_size, void* d_ws, size_t ws_size,
                              hipStream_t stream) {
    const float* x    = (const float*)d_in[1];   // [8192, 512]
    const int*   ei   = (const int*)  d_in[2];   // [2, 262144] (int32 on device)
    const float* Wlin = (const float*)d_in[3];   // [256, 512]
    const float* blin = (const float*)d_in[4];   // [256]
    const float* Watt = (const float*)d_in[5];   // [512]

    float* out0 = (float*)d_out;                         // [8192, 8192]
    float* hout = out0 + (size_t)N_NODES * N_NODES;      // [8192, 256]

    unsigned short* Wbf = (unsigned short*)d_ws;          // 256 KB bf16 W
    float* s = (float*)((char*)d_ws + NHID * NFEAT * sizeof(unsigned short));
    float* t = s + N_NODES;

    // Zero the dense adjacency output (~44 us, write-BW floor).
    hipMemsetAsync(out0, 0, (size_t)N_NODES * N_NODES * sizeof(float), stream);

    convw_kernel<<<(NHID * NFEAT / 4) / 256, 256, 0, stream>>>(Wlin, Wbf);

    gemm_fused_kernel<<<N_NODES / 64, 256, 0, stream>>>(
        x, Wbf, blin, Watt, hout, s, t);

    edge_kernel<<<E_EDGES / 256, 256, 0, stream>>>(ei, s, t, out0);
}

// Round 4
// 465.933 us; speedup vs baseline: 1.0271x; 1.0271x over previous
//
#include <hip/hip_runtime.h>
#include <hip/hip_bf16.h>
#include <cmath>

#define N_NODES 8192
#define E_EDGES 262144
#define NFEAT   512
#define NHID    256

typedef __attribute__((ext_vector_type(8))) short short8;
typedef __attribute__((ext_vector_type(4))) float f32x4;
typedef __attribute__((ext_vector_type(4))) short short4v;

// f32 -> bf16 round-to-nearest-even
static __device__ inline unsigned short f2bf(float f) {
    union { float f; unsigned u; } v; v.f = f;
    unsigned r = v.u + 0x7FFFu + ((v.u >> 16) & 1u);
    return (unsigned short)(r >> 16);
}

// ---------------------------------------------------------------------------
// W_lin [256,512] f32 -> bf16 once per launch (reused by all 512 strips).
// ---------------------------------------------------------------------------
__global__ __launch_bounds__(256) void convw_kernel(
        const float* __restrict__ W, unsigned short* __restrict__ Wbf) {
    const int i = (blockIdx.x * 256 + threadIdx.x) * 4;
    const float4 w = *reinterpret_cast<const float4*>(&W[i]);
    short4v o;
    o[0] = (short)f2bf(w.x); o[1] = (short)f2bf(w.y);
    o[2] = (short)f2bf(w.z); o[3] = (short)f2bf(w.w);
    *reinterpret_cast<short4v*>(&Wbf[i]) = o;
}

// ---------------------------------------------------------------------------
// Fused h = x @ W^T + b  (bf16 MFMA) + s,t = h . W_att halves.
// 512 blocks (one 16-row strip each) x 4 waves; wave w owns n-tiles 4w..4w+3.
// 8 waves/CU occupancy (vs 2 before).  mfma_f32_16x16x32_bf16, m89 layout:
//   A: lane l holds A[l&15][(l>>4)*8+j]; C/D: lane l reg j = D[(l>>4)*4+j][l&15]
// ---------------------------------------------------------------------------
__global__ __launch_bounds__(256) void gemm_fused_kernel(
        const float* __restrict__ x,            // [8192, 512]
        const unsigned short* __restrict__ Wbf, // [256, 512] bf16
        const float* __restrict__ b,            // [256]
        const float* __restrict__ Wa,           // [512]
        float* __restrict__ hout,               // [8192, 256]
        float* __restrict__ s, float* __restrict__ t) {
    const int lane = threadIdx.x & 63;
    const int wave = threadIdx.x >> 6;           // 0..3
    const int r    = lane & 15;
    const int kg   = lane >> 4;                  // 0..3
    const int m0   = blockIdx.x * 16;            // strip base row

    __shared__ float sred[4][16], tred[4][16];

    f32x4 acc[4];
    #pragma unroll
    for (int q = 0; q < 4; ++q) acc[q] = (f32x4)0.0f;

    const float* xrow = x + (size_t)(m0 + r) * NFEAT + kg * 8;

    #pragma unroll 4
    for (int ks = 0; ks < NFEAT / 32; ++ks) {
        const int k0 = ks * 32;
        short8 af;
        {
            const float4 a0 = *reinterpret_cast<const float4*>(xrow + k0);
            const float4 a1 = *reinterpret_cast<const float4*>(xrow + k0 + 4);
            af[0] = (short)f2bf(a0.x); af[1] = (short)f2bf(a0.y);
            af[2] = (short)f2bf(a0.z); af[3] = (short)f2bf(a0.w);
            af[4] = (short)f2bf(a1.x); af[5] = (short)f2bf(a1.y);
            af[6] = (short)f2bf(a1.z); af[7] = (short)f2bf(a1.w);
        }
        #pragma unroll
        for (int q = 0; q < 4; ++q) {
            const int nt = wave * 4 + q;
            const short8 bf = *reinterpret_cast<const short8*>(
                &Wbf[(size_t)(nt * 16 + r) * NFEAT + k0 + kg * 8]);
            acc[q] = __builtin_amdgcn_mfma_f32_16x16x32_bf16(af, bf, acc[q], 0, 0, 0);
        }
    }

    // Epilogue: bias + h store + per-wave partial s/t dots over its 64 cols.
    float sp[4] = {0.f, 0.f, 0.f, 0.f};
    float tp[4] = {0.f, 0.f, 0.f, 0.f};
    #pragma unroll
    for (int q = 0; q < 4; ++q) {
        const int n = (wave * 4 + q) * 16 + r;
        const float bb  = b[n];
        const float was = Wa[n];
        const float wat = Wa[NHID + n];
        #pragma unroll
        for (int j = 0; j < 4; ++j) {
            const float hv = acc[q][j] + bb;
            hout[(size_t)(m0 + kg * 4 + j) * NHID + n] = hv;
            sp[j] = fmaf(hv, was, sp[j]);
            tp[j] = fmaf(hv, wat, tp[j]);
        }
    }
    #pragma unroll
    for (int off = 1; off < 16; off <<= 1) {
        #pragma unroll
        for (int j = 0; j < 4; ++j) {
            sp[j] += __shfl_xor(sp[j], off);
            tp[j] += __shfl_xor(tp[j], off);
        }
    }
    if (r == 0) {                         // lanes 0,16,32,48: rows kg*4+j
        #pragma unroll
        for (int j = 0; j < 4; ++j) {
            sred[wave][kg * 4 + j] = sp[j];
            tred[wave][kg * 4 + j] = tp[j];
        }
    }
    __syncthreads();
    if (threadIdx.x < 16) {               // wave 0 sums the 4 wave-partials
        const int row = threadIdx.x;
        float ss = sred[0][row] + sred[1][row] + sred[2][row] + sred[3][row];
        float tt = tred[0][row] + tred[1][row] + tred[2][row] + tred[3][row];
        s[m0 + row] = ss;
        t[m0 + row] = tt;
    }
}

// ---------------------------------------------------------------------------
// CSR build: counts -> exclusive scan -> column scatter. (~4 us total)
// ---------------------------------------------------------------------------
__global__ __launch_bounds__(256) void count_kernel(
        const int* __restrict__ ei, int* __restrict__ counts) {
    const int e = blockIdx.x * 256 + threadIdx.x;
    atomicAdd(&counts[ei[e]], 1);
}

__global__ __launch_bounds__(256) void scan_kernel(
        const int* __restrict__ counts, int* __restrict__ offsets,
        int* __restrict__ cursor) {
    __shared__ int ssum[256];
    const int t = threadIdx.x;
    int local[32];
    int run = 0;
    #pragma unroll
    for (int i = 0; i < 32; ++i) { local[i] = run; run += counts[t * 32 + i]; }
    ssum[t] = run;
    __syncthreads();
    for (int off = 1; off < 256; off <<= 1) {
        int v = ssum[t];
        if (t >= off) v += ssum[t - off];
        __syncthreads();
        ssum[t] = v;
        __syncthreads();
    }
    const int base = (t == 0) ? 0 : ssum[t - 1];
    #pragma unroll
    for (int i = 0; i < 32; ++i) {
        const int o = base + local[i];
        offsets[t * 32 + i] = o;
        cursor [t * 32 + i] = o;
    }
    if (t == 255) offsets[N_NODES] = ssum[255];
}

__global__ __launch_bounds__(256) void scatter_kernel(
        const int* __restrict__ ei, int* __restrict__ cursor,
        int* __restrict__ col) {
    const int e = blockIdx.x * 256 + threadIdx.x;
    const int src = ei[e];
    const int dst = ei[E_EDGES + e];
    const int pos = atomicAdd(&cursor[src], 1);
    col[pos] = dst;
}

// ---------------------------------------------------------------------------
// Dense writer: one block per output row. Zero the row with full-line float4
// stores, then overwrite this row's edges with tanh(s[row]+t[dst]).
// Every output line written exactly once -> no RMW fetch, no separate memset.
// adj==1.0 at every edge by construction, so no adj gather.
// ---------------------------------------------------------------------------
__global__ __launch_bounds__(256) void dense_kernel(
        const int* __restrict__ offsets, const int* __restrict__ col,
        const float* __restrict__ s, const float* __restrict__ t,
        float* __restrict__ out) {
    const int row = blockIdx.x;
    float* orow = out + (size_t)row * N_NODES;
    const f32x4 z = (f32x4)0.0f;
    #pragma unroll
    for (int j = 0; j < 8; ++j)
        *reinterpret_cast<f32x4*>(orow + (threadIdx.x + j * 256) * 4) = z;
    __syncthreads();
    const int beg = offsets[row], end = offsets[row + 1];
    const float sr = s[row];
    for (int k = beg + (int)threadIdx.x; k < end; k += 256) {
        const int dst = col[k];
        orow[dst] = tanhf(sr + t[dst]);
    }
}

extern "C" void kernel_launch(void* const* d_in, const int* in_sizes, int n_in,
                              void* d_out, int out_size, void* d_ws, size_t ws_size,
                              hipStream_t stream) {
    const float* x    = (const float*)d_in[1];   // [8192, 512]
    const int*   ei   = (const int*)  d_in[2];   // [2, 262144] int32
    const float* Wlin = (const float*)d_in[3];   // [256, 512]
    const float* blin = (const float*)d_in[4];   // [256]
    const float* Watt = (const float*)d_in[5];   // [512]

    float* out0 = (float*)d_out;                        // [8192, 8192]
    float* hout = out0 + (size_t)N_NODES * N_NODES;     // [8192, 256]

    // ws layout
    char* w = (char*)d_ws;
    unsigned short* Wbf = (unsigned short*)w;  w += NHID * NFEAT * sizeof(unsigned short);
    float* s       = (float*)w;                w += N_NODES * sizeof(float);
    float* t       = (float*)w;                w += N_NODES * sizeof(float);
    int*   counts  = (int*)w;                  w += N_NODES * sizeof(int);
    int*   offsets = (int*)w;                  w += (N_NODES + 1) * sizeof(int);
    int*   cursor  = (int*)w;                  w += N_NODES * sizeof(int);
    int*   col     = (int*)w;

    // CSR build (independent of GEMM; stream-ordered anyway).
    hipMemsetAsync(counts, 0, N_NODES * sizeof(int), stream);
    count_kernel  <<<E_EDGES / 256, 256, 0, stream>>>(ei, counts);
    scan_kernel   <<<1, 256, 0, stream>>>(counts, offsets, cursor);
    scatter_kernel<<<E_EDGES / 256, 256, 0, stream>>>(ei, cursor, col);

    convw_kernel<<<(NHID * NFEAT / 4) / 256, 256, 0, stream>>>(Wlin, Wbf);
    gemm_fused_kernel<<<N_NODES / 16, 256, 0, stream>>>(
        x, Wbf, blin, Watt, hout, s, t);

    dense_kernel<<<N_NODES, 256, 0, stream>>>(offsets, col, s, t, out0);
}